// Round 8
// baseline (458.803 us; speedup 1.0000x reference)
//
#include <hip/hip_runtime.h>

typedef __bf16 bf16;
typedef __bf16 bf16x8 __attribute__((ext_vector_type(8)));
typedef __bf16 bf16x4 __attribute__((ext_vector_type(4)));
typedef float  f32x4  __attribute__((ext_vector_type(4)));

#define MFMA16(a, b, c) __builtin_amdgcn_mfma_f32_16x16x32_bf16((a), (b), (c), 0, 0, 0)

// Hard ordering for same-wave cross-lane LDS exchange.
#define LDS_FENCE() __asm__ volatile("s_waitcnt lgkmcnt(0)" ::: "memory")

// ---------------- prep: fold weights (fp32 in -> bf16 staged) ----------------
// W_A = out_w @ Wv  (Wv = in_proj_w[256:384,:]),  b_A = out_w @ bv + out_b (fp32)
// Wmats[0] = W1eff (fuse_w1 K-collapsed), [1]=fuse_w2, [2]=upd_w1, [3]=upd_w2
__global__ void prep_kernel(const float* __restrict__ in_proj_w,
                            const float* __restrict__ in_proj_b,
                            const float* __restrict__ out_w,
                            const float* __restrict__ out_b,
                            const float* __restrict__ fuse_w1,
                            const float* __restrict__ fuse_w2,
                            const float* __restrict__ upd_w1,
                            const float* __restrict__ upd_w2,
                            bf16* __restrict__ W_A,
                            bf16* __restrict__ Wmats,
                            float* __restrict__ b_A) {
    const int i = blockIdx.x;   // output row 0..127
    const int k = threadIdx.x;  // col 0..127
    float accW = 0.f;
    for (int j = 0; j < 128; ++j)
        accW += out_w[i * 128 + j] * in_proj_w[(256 + j) * 128 + k];
    W_A[i * 128 + k] = (bf16)accW;
    float accE = 0.f;
    for (int j = 0; j < 8; ++j)
        accE += fuse_w1[i * 1024 + j * 128 + k];
    Wmats[0 * 16384 + i * 128 + k] = (bf16)accE;
    Wmats[1 * 16384 + i * 128 + k] = (bf16)fuse_w2[i * 128 + k];
    Wmats[2 * 16384 + i * 128 + k] = (bf16)upd_w1[i * 128 + k];
    Wmats[3 * 16384 + i * 128 + k] = (bf16)upd_w2[i * 128 + k];
    if (k == 0) {
        float accB = out_b[i];
        for (int j = 0; j < 128; ++j)
            accB += out_w[i * 128 + j] * in_proj_b[256 + j];
        b_A[i] = accB;
    }
}

// ---------------- shared geometry ----------------
constexpr int STG_STRIDE  = 128;              // bytes per batch-row (64 bf16)
constexpr int STG_BYTES   = 16 * STG_STRIDE;  // 2048 per wave

// ---------------- primary: 1024 thr, weights in LDS (160 KiB) ----------------
constexpr int THREADS     = 1024;  // 16 waves -> 4 waves/SIMD at 1 block/CU
constexpr int WAVES       = 16;
constexpr int LDS_W       = 32768;            // one 128x128 bf16 matrix
constexpr int LDS_WEIGHTS = 4 * LDS_W;        // 131072
constexpr int LDS_TOTAL   = LDS_WEIGHTS + WAVES * STG_BYTES;  // 163840 = 160 KiB
constexpr int N_IT        = 2;
constexpr int SLOTS       = 256 * WAVES;      // wave-slots per iteration

// Round-1/2 evidence: hipcc's occupancy heuristic (blind to dynamic LDS)
// targets 8 waves/EU for 1024-thread blocks -> 64 VGPR -> scratch spills
// (FETCH+WRITE ballooned ~450 MB). amdgpu_waves_per_eu(4,4) pins exactly
// 4 waves/EU -> 128-VGPR budget. Host code verifies via hipFuncGetAttributes
// and falls back to fsl_main_g if the allocator still spilled.
__global__ __launch_bounds__(THREADS)
__attribute__((amdgpu_waves_per_eu(4, 4)))
void fsl_main(const float* __restrict__ x,
              const bf16* __restrict__ W_A,
              const float* __restrict__ b_A,
              const bf16* __restrict__ Wmats,
              const float* __restrict__ fuse_b1,
              const float* __restrict__ fuse_b2,
              const float* __restrict__ upd_b1,
              const float* __restrict__ upd_b2,
              float* __restrict__ out) {
    extern __shared__ __align__(16) char smem[];
    const int tid  = threadIdx.x;
    const int lane = tid & 63;
    const int wave = tid >> 6;
    const int c    = lane & 15;  // batch col (B-op) / weight row-in-tile (A-op)
    const int q    = lane >> 4;  // k-group 0..3

    // insurance: no LDS byte is ever "uninitialized garbage" (one-time cost)
    {
        uint4 z = {0u, 0u, 0u, 0u};
        for (int i = tid; i < LDS_TOTAL / 16; i += THREADS)
            ((uint4*)smem)[i] = z;
    }
    __syncthreads();

    // cooperative load of 4 weight matrices (bf16, pre-converted by prep),
    // 16B-granule XOR swizzle: granule gk of row m lives at (gk ^ (m&7))
    for (int g = tid; g < 4 * 128 * 16; g += THREADS) {
        const int s  = g >> 11;
        const int m  = (g >> 4) & 127;
        const int gk = g & 15;
        uint4 v = *(const uint4*)(Wmats + s * 16384 + m * 128 + gk * 8);
        *(uint4*)(smem + s * LDS_W + m * 256 + ((gk ^ (m & 7)) * 16)) = v;
    }
    __syncthreads();

    char* const stg = smem + LDS_WEIGHTS + wave * STG_BYTES;
    const int wslot = blockIdx.x * WAVES + wave;  // 0..4095

    for (int it = 0; it < N_IT; ++it) {
        const int blk  = wslot + it * SLOTS;  // 0..8191
        const int row0 = blk * 32;

        bf16x8 Xf[2][4], Af[2][4], Hf[2][4];
        f32x4  acc[2][8];

        // X as B-fragments: lane reads x[row0+u*16+c][t*32+q*8 .. +7], fp32 -> bf16
#pragma unroll
        for (int u = 0; u < 2; ++u) {
            const float* xr = x + (row0 + u * 16 + c) * 128 + q * 8;
#pragma unroll
            for (int t = 0; t < 4; ++t) {
                f32x4 lo = *(const f32x4*)(xr + t * 32);
                f32x4 hi = *(const f32x4*)(xr + t * 32 + 4);
                bf16x8 f;
#pragma unroll
                for (int j = 0; j < 4; ++j) {
                    f[j]     = (bf16)lo[j];
                    f[4 + j] = (bf16)hi[j];
                }
                Xf[u][t] = f;
            }
        }

        auto zero_acc = [&]() {
#pragma unroll
            for (int u = 0; u < 2; ++u)
#pragma unroll
                for (int mt = 0; mt < 8; ++mt)
                    acc[u][mt] = f32x4{0.f, 0.f, 0.f, 0.f};
        };

        // C^T = W * act^T : weight rows are the A-operand (contiguous 16B/lane)
        auto gemm_global = [&](const bf16* W, bf16x8 (&in)[2][4]) {
            zero_acc();
#pragma unroll
            for (int mt = 0; mt < 8; ++mt) {
                const bf16* wrow = W + (mt * 16 + c) * 128 + q * 8;
#pragma unroll
                for (int t = 0; t < 4; ++t) {
                    bf16x8 wf = *(const bf16x8*)(wrow + t * 32);
#pragma unroll
                    for (int u = 0; u < 2; ++u)
                        acc[u][mt] = MFMA16(wf, in[u][t], acc[u][mt]);
                }
            }
        };

        auto gemm_lds = [&](int s, bf16x8 (&in)[2][4]) {
            zero_acc();
#pragma unroll
            for (int mt = 0; mt < 8; ++mt) {
                const int m = mt * 16 + c;
                const char* wrow = smem + s * LDS_W + m * 256;
                const int msw = m & 7;
#pragma unroll
                for (int t = 0; t < 4; ++t) {
                    bf16x8 wf = *(const bf16x8*)(wrow + (((t * 4 + q) ^ msw) * 16));
#pragma unroll
                    for (int u = 0; u < 2; ++u)
                        acc[u][mt] = MFMA16(wf, in[u][t], acc[u][mt]);
                }
            }
        };

        // C-space: +bias(fp32) (and relu), pack to bf16, LDS round-trip to
        // B-frag layout; optional residual add; dst regs or fp32 global store.
        auto transition = [&](const float* bias, bool relu, bf16x8 (*resid)[4],
                              bf16x8 (*dst)[4], bool to_global) {
#pragma unroll
            for (int u = 0; u < 2; ++u) {
#pragma unroll
                for (int p = 0; p < 2; ++p) {  // hidden halves [64p, 64p+64)
#pragma unroll
                    for (int mi = 0; mi < 4; ++mi) {
                        const int mt = 4 * p + mi;
                        f32x4 a = acc[u][mt];
                        f32x4 bv = *(const f32x4*)(bias + mt * 16 + q * 4);
#pragma unroll
                        for (int r = 0; r < 4; ++r) {
                            float v = a[r] + bv[r];
                            if (relu) v = v > 0.f ? v : 0.f;
                            a[r] = v;
                        }
                        bf16x4 pk = {(bf16)a[0], (bf16)a[1], (bf16)a[2], (bf16)a[3]};
                        const int hl = mi * 16 + q * 4;  // local hidden 0..60
                        *(bf16x4*)(stg + c * STG_STRIDE + (((hl >> 3) ^ (c & 7)) * 16) +
                                   (hl & 7) * 2) = pk;
                    }
                    LDS_FENCE();  // cross-lane: writes visible before reads
#pragma unroll
                    for (int ti = 0; ti < 2; ++ti) {
                        const int t  = 2 * p + ti;
                        const int kl = ti * 32 + q * 8;
                        bf16x8 sv = *(const bf16x8*)(stg + c * STG_STRIDE +
                                                     (((kl >> 3) ^ (c & 7)) * 16));
                        if (to_global) {
                            float* orow = out + (row0 + u * 16 + c) * 128 + t * 32 + q * 8;
                            bf16x8 rv = resid[u][t];
                            f32x4 lo, hi;
#pragma unroll
                            for (int j = 0; j < 4; ++j) {
                                lo[j] = (float)sv[j]     + (float)rv[j];
                                hi[j] = (float)sv[4 + j] + (float)rv[4 + j];
                            }
                            *(f32x4*)(orow)     = lo;
                            *(f32x4*)(orow + 4) = hi;
                        } else {
                            if (resid) {
                                bf16x8 rv = resid[u][t];
                                bf16x8 o;
#pragma unroll
                                for (int j = 0; j < 8; ++j)
                                    o[j] = (bf16)((float)sv[j] + (float)rv[j]);
                                sv = o;
                            }
                            dst[u][t] = sv;
                        }
                    }
                    LDS_FENCE();  // reads drained before next overwrite (WAR)
                }
            }
        };

        // stage 1: A = W_A x^T + b_A            (weights from global/L2)
        gemm_global(W_A, Xf);
        transition(b_A, false, nullptr, Af, false);
        // stage 2: h = relu(W1eff A^T + b1)
        gemm_lds(0, Af);
        transition(fuse_b1, true, nullptr, Hf, false);
        // stage 3: Ahat = fuse_w2 h^T + b2 + A
        gemm_lds(1, Hf);
        transition(fuse_b2, false, Af, Hf, false);
        // stage 4: h2 = relu(upd_w1 Ahat^T + b3)
        gemm_lds(2, Hf);
        transition(upd_b1, true, nullptr, Af, false);
        // stage 5: out = upd_w2 h2^T + b4 + x   -> fp32 global
        gemm_lds(3, Af);
        transition(upd_b2, false, Xf, nullptr, true);
    }
}

// ------------- fallback: 512 thr, ALL weights from global/L2, 16 KiB LDS ----
// Round-0-verified codegen config: __launch_bounds__(512, 2) measured
// 128 VGPR / zero spills. 16 KiB LDS -> 2 blocks/CU (VGPR-capped) =
// 16 waves/CU = 4 waves/SIMD. Weights (160 KiB total) stay L2-resident.
constexpr int THREADS_G = 512;
constexpr int WAVES_G   = 8;
constexpr int LDS_TOTAL_G = WAVES_G * STG_BYTES;  // 16384
constexpr int GRID_G    = 512;
constexpr int SLOTS_G   = GRID_G * WAVES_G;       // 4096
constexpr int N_IT_G    = 2;                      // 512*8*2*32 = 262144 rows

__global__ __launch_bounds__(THREADS_G, 2)
void fsl_main_g(const float* __restrict__ x,
                const bf16* __restrict__ W_A,
                const float* __restrict__ b_A,
                const bf16* __restrict__ Wmats,
                const float* __restrict__ fuse_b1,
                const float* __restrict__ fuse_b2,
                const float* __restrict__ upd_b1,
                const float* __restrict__ upd_b2,
                float* __restrict__ out) {
    extern __shared__ __align__(16) char smem[];
    const int tid  = threadIdx.x;
    const int lane = tid & 63;
    const int wave = tid >> 6;
    const int c    = lane & 15;
    const int q    = lane >> 4;

    {
        uint4 z = {0u, 0u, 0u, 0u};
        for (int i = tid; i < LDS_TOTAL_G / 16; i += THREADS_G)
            ((uint4*)smem)[i] = z;
    }
    __syncthreads();

    char* const stg = smem + wave * STG_BYTES;
    const int wslot = blockIdx.x * WAVES_G + wave;  // 0..4095

    for (int it = 0; it < N_IT_G; ++it) {
        const int blk  = wslot + it * SLOTS_G;  // 0..8191
        const int row0 = blk * 32;

        bf16x8 Xf[2][4], Af[2][4], Hf[2][4];
        f32x4  acc[2][8];

#pragma unroll
        for (int u = 0; u < 2; ++u) {
            const float* xr = x + (row0 + u * 16 + c) * 128 + q * 8;
#pragma unroll
            for (int t = 0; t < 4; ++t) {
                f32x4 lo = *(const f32x4*)(xr + t * 32);
                f32x4 hi = *(const f32x4*)(xr + t * 32 + 4);
                bf16x8 f;
#pragma unroll
                for (int j = 0; j < 4; ++j) {
                    f[j]     = (bf16)lo[j];
                    f[4 + j] = (bf16)hi[j];
                }
                Xf[u][t] = f;
            }
        }

        auto zero_acc = [&]() {
#pragma unroll
            for (int u = 0; u < 2; ++u)
#pragma unroll
                for (int mt = 0; mt < 8; ++mt)
                    acc[u][mt] = f32x4{0.f, 0.f, 0.f, 0.f};
        };

        auto gemm_global = [&](const bf16* W, bf16x8 (&in)[2][4]) {
            zero_acc();
#pragma unroll
            for (int mt = 0; mt < 8; ++mt) {
                const bf16* wrow = W + (mt * 16 + c) * 128 + q * 8;
#pragma unroll
                for (int t = 0; t < 4; ++t) {
                    bf16x8 wf = *(const bf16x8*)(wrow + t * 32);
#pragma unroll
                    for (int u = 0; u < 2; ++u)
                        acc[u][mt] = MFMA16(wf, in[u][t], acc[u][mt]);
                }
            }
        };

        auto transition = [&](const float* bias, bool relu, bf16x8 (*resid)[4],
                              bf16x8 (*dst)[4], bool to_global) {
#pragma unroll
            for (int u = 0; u < 2; ++u) {
#pragma unroll
                for (int p = 0; p < 2; ++p) {
#pragma unroll
                    for (int mi = 0; mi < 4; ++mi) {
                        const int mt = 4 * p + mi;
                        f32x4 a = acc[u][mt];
                        f32x4 bv = *(const f32x4*)(bias + mt * 16 + q * 4);
#pragma unroll
                        for (int r = 0; r < 4; ++r) {
                            float v = a[r] + bv[r];
                            if (relu) v = v > 0.f ? v : 0.f;
                            a[r] = v;
                        }
                        bf16x4 pk = {(bf16)a[0], (bf16)a[1], (bf16)a[2], (bf16)a[3]};
                        const int hl = mi * 16 + q * 4;
                        *(bf16x4*)(stg + c * STG_STRIDE + (((hl >> 3) ^ (c & 7)) * 16) +
                                   (hl & 7) * 2) = pk;
                    }
                    LDS_FENCE();
#pragma unroll
                    for (int ti = 0; ti < 2; ++ti) {
                        const int t  = 2 * p + ti;
                        const int kl = ti * 32 + q * 8;
                        bf16x8 sv = *(const bf16x8*)(stg + c * STG_STRIDE +
                                                     (((kl >> 3) ^ (c & 7)) * 16));
                        if (to_global) {
                            float* orow = out + (row0 + u * 16 + c) * 128 + t * 32 + q * 8;
                            bf16x8 rv = resid[u][t];
                            f32x4 lo, hi;
#pragma unroll
                            for (int j = 0; j < 4; ++j) {
                                lo[j] = (float)sv[j]     + (float)rv[j];
                                hi[j] = (float)sv[4 + j] + (float)rv[4 + j];
                            }
                            *(f32x4*)(orow)     = lo;
                            *(f32x4*)(orow + 4) = hi;
                        } else {
                            if (resid) {
                                bf16x8 rv = resid[u][t];
                                bf16x8 o;
#pragma unroll
                                for (int j = 0; j < 8; ++j)
                                    o[j] = (bf16)((float)sv[j] + (float)rv[j]);
                                sv = o;
                            }
                            dst[u][t] = sv;
                        }
                    }
                    LDS_FENCE();
                }
            }
        };

        gemm_global(W_A, Xf);
        transition(b_A, false, nullptr, Af, false);
        gemm_global(Wmats + 0 * 16384, Af);
        transition(fuse_b1, true, nullptr, Hf, false);
        gemm_global(Wmats + 1 * 16384, Hf);
        transition(fuse_b2, false, Af, Hf, false);
        gemm_global(Wmats + 2 * 16384, Hf);
        transition(upd_b1, true, nullptr, Af, false);
        gemm_global(Wmats + 3 * 16384, Af);
        transition(upd_b2, false, Xf, nullptr, true);
    }
}

extern "C" void kernel_launch(void* const* d_in, const int* in_sizes, int n_in,
                              void* d_out, int out_size, void* d_ws, size_t ws_size,
                              hipStream_t stream) {
    const float* task      = (const float*)d_in[0];
    const float* in_proj_w = (const float*)d_in[1];
    const float* in_proj_b = (const float*)d_in[2];
    const float* out_w     = (const float*)d_in[3];
    const float* out_b     = (const float*)d_in[4];
    const float* fuse_w1   = (const float*)d_in[5];
    const float* fuse_b1   = (const float*)d_in[6];
    const float* fuse_w2   = (const float*)d_in[7];
    const float* fuse_b2   = (const float*)d_in[8];
    const float* upd_w1    = (const float*)d_in[9];
    const float* upd_b1    = (const float*)d_in[10];
    const float* upd_w2    = (const float*)d_in[11];
    const float* upd_b2    = (const float*)d_in[12];
    float* out = (float*)d_out;

    // ws layout: W_A (16384 bf16) | Wmats (4*16384 bf16) | b_A (128 f32)
    bf16*  W_A   = (bf16*)d_ws;
    bf16*  Wmats = W_A + 16384;
    float* b_A   = (float*)((char*)d_ws + 32768 + 131072);

    (void)in_sizes; (void)n_in; (void)out_size; (void)ws_size;

    prep_kernel<<<128, 128, 0, stream>>>(in_proj_w, in_proj_b, out_w, out_b,
                                         fuse_w1, fuse_w2, upd_w1, upd_w2,
                                         W_A, Wmats, b_A);

    // Select main kernel based on what the register allocator actually did
    // (host-side attribute query; no stream ops -> graph-capture safe).
    hipFuncAttributes fa{};
    bool use_primary = false;
    if (hipFuncGetAttributes(&fa, (const void*)fsl_main) == hipSuccess)
        use_primary = (fa.numRegs >= 96) && (fa.localSizeBytes == 0);

    if (use_primary) {
        hipFuncSetAttribute((const void*)fsl_main,
                            hipFuncAttributeMaxDynamicSharedMemorySize, LDS_TOTAL);
        fsl_main<<<256, THREADS, LDS_TOTAL, stream>>>(task, W_A, b_A, Wmats,
                                                      fuse_b1, fuse_b2, upd_b1,
                                                      upd_b2, out);
    } else {
        fsl_main_g<<<GRID_G, THREADS_G, LDS_TOTAL_G, stream>>>(task, W_A, b_A,
                                                               Wmats, fuse_b1,
                                                               fuse_b2, upd_b1,
                                                               upd_b2, out);
    }
}

// Round 11
// 362.720 us; speedup vs baseline: 1.2649x; 1.2649x over previous
//
#include <hip/hip_runtime.h>

typedef __bf16 bf16;
typedef __bf16 bf16x8 __attribute__((ext_vector_type(8)));
typedef __bf16 bf16x4 __attribute__((ext_vector_type(4)));
typedef float  f32x4  __attribute__((ext_vector_type(4)));

#define MFMA16(a, b, c) __builtin_amdgcn_mfma_f32_16x16x32_bf16((a), (b), (c), 0, 0, 0)

// Hard ordering for same-wave cross-lane LDS exchange.
#define LDS_FENCE() __asm__ volatile("s_waitcnt lgkmcnt(0)" ::: "memory")

// ---------------- prep: fold weights (fp32 in -> bf16 staged) ----------------
__global__ void prep_kernel(const float* __restrict__ in_proj_w,
                            const float* __restrict__ in_proj_b,
                            const float* __restrict__ out_w,
                            const float* __restrict__ out_b,
                            const float* __restrict__ fuse_w1,
                            const float* __restrict__ fuse_w2,
                            const float* __restrict__ upd_w1,
                            const float* __restrict__ upd_w2,
                            bf16* __restrict__ W_A,
                            bf16* __restrict__ Wmats,
                            float* __restrict__ b_A) {
    const int i = blockIdx.x;   // output row 0..127
    const int k = threadIdx.x;  // col 0..127
    float accW = 0.f;
    for (int j = 0; j < 128; ++j)
        accW += out_w[i * 128 + j] * in_proj_w[(256 + j) * 128 + k];
    W_A[i * 128 + k] = (bf16)accW;
    float accE = 0.f;
    for (int j = 0; j < 8; ++j)
        accE += fuse_w1[i * 1024 + j * 128 + k];
    Wmats[0 * 16384 + i * 128 + k] = (bf16)accE;
    Wmats[1 * 16384 + i * 128 + k] = (bf16)fuse_w2[i * 128 + k];
    Wmats[2 * 16384 + i * 128 + k] = (bf16)upd_w1[i * 128 + k];
    Wmats[3 * 16384 + i * 128 + k] = (bf16)upd_w2[i * 128 + k];
    if (k == 0) {
        float accB = out_b[i];
        for (int j = 0; j < 128; ++j)
            accB += out_w[i * 128 + j] * in_proj_b[256 + j];
        b_A[i] = accB;
    }
}

// ---------------- shared geometry ----------------
constexpr int STG_STRIDE  = 128;              // bytes per batch-row (64 bf16)
constexpr int STG_BYTES   = 16 * STG_STRIDE;  // 2048 per wave
constexpr int LDS_W       = 32768;            // one 128x128 bf16 matrix
constexpr int LDS_WEIGHTS = 4 * LDS_W;        // 131072

// ---------------- primary: u=1 slim waves, 1024 thr, weights in LDS ---------
// Round-8 evidence: the u=2 structure's true per-wave footprint is ~192 regs
// (128 arch-VGPR + ~64 AGPR acc; rocprof VGPR_Count excludes AGPRs) ->
// 4 waves/SIMD only via spills. u=1 halves live state (Xf/Af/Hf 48 + acc 32
// + addressing ~= 110-120 regs) -> fits the 128-budget that
// amdgpu_waves_per_eu(4,4) pins, spill-free. 16-wave block, 160 KiB LDS,
// 1 block/CU = 4 waves/SIMD.
constexpr int THREADS   = 1024;
constexpr int WAVES     = 16;
constexpr int LDS_TOTAL = LDS_WEIGHTS + WAVES * STG_BYTES;  // 163840 = 160 KiB
constexpr int N_IT      = 4;
constexpr int SLOTS     = 256 * WAVES;  // 4096 wave slots; 4096*4*16 = 262144 rows

__global__ __launch_bounds__(THREADS)
__attribute__((amdgpu_waves_per_eu(4, 4)))
void fsl_main(const float* __restrict__ x,
              const bf16* __restrict__ W_A,
              const float* __restrict__ b_A,
              const bf16* __restrict__ Wmats,
              const float* __restrict__ fuse_b1,
              const float* __restrict__ fuse_b2,
              const float* __restrict__ upd_b1,
              const float* __restrict__ upd_b2,
              float* __restrict__ out) {
    extern __shared__ __align__(16) char smem[];
    const int tid  = threadIdx.x;
    const int lane = tid & 63;
    const int wave = tid >> 6;
    const int c    = lane & 15;  // batch col (B-op) / weight row-in-tile (A-op)
    const int q    = lane >> 4;  // k-group 0..3

    {
        uint4 z = {0u, 0u, 0u, 0u};
        for (int i = tid; i < LDS_TOTAL / 16; i += THREADS)
            ((uint4*)smem)[i] = z;
    }
    __syncthreads();

    // cooperative load of 4 weight matrices, 16B-granule XOR swizzle
    for (int g = tid; g < 4 * 128 * 16; g += THREADS) {
        const int s  = g >> 11;
        const int m  = (g >> 4) & 127;
        const int gk = g & 15;
        uint4 v = *(const uint4*)(Wmats + s * 16384 + m * 128 + gk * 8);
        *(uint4*)(smem + s * LDS_W + m * 256 + ((gk ^ (m & 7)) * 16)) = v;
    }
    __syncthreads();

    char* const stg = smem + LDS_WEIGHTS + wave * STG_BYTES;
    const int wslot = blockIdx.x * WAVES + wave;  // 0..4095

    for (int it = 0; it < N_IT; ++it) {
        const int blk  = wslot + it * SLOTS;  // 0..16383
        const int row0 = blk * 16;

        bf16x8 Xf[4], Af[4], Hf[4];
        f32x4  acc[8];

        // X as B-fragments: lane reads x[row0+c][t*32+q*8 .. +7], fp32 -> bf16
        {
            const float* xr = x + (row0 + c) * 128 + q * 8;
#pragma unroll
            for (int t = 0; t < 4; ++t) {
                f32x4 lo = *(const f32x4*)(xr + t * 32);
                f32x4 hi = *(const f32x4*)(xr + t * 32 + 4);
                bf16x8 f;
#pragma unroll
                for (int j = 0; j < 4; ++j) {
                    f[j]     = (bf16)lo[j];
                    f[4 + j] = (bf16)hi[j];
                }
                Xf[t] = f;
            }
        }

        auto zero_acc = [&]() {
#pragma unroll
            for (int mt = 0; mt < 8; ++mt)
                acc[mt] = f32x4{0.f, 0.f, 0.f, 0.f};
        };

        // C^T = W * act^T : weight rows are the A-operand (contiguous 16B/lane)
        auto gemm_global = [&](const bf16* W, bf16x8* in) {
            zero_acc();
#pragma unroll
            for (int mt = 0; mt < 8; ++mt) {
                const bf16* wrow = W + (mt * 16 + c) * 128 + q * 8;
#pragma unroll
                for (int t = 0; t < 4; ++t) {
                    bf16x8 wf = *(const bf16x8*)(wrow + t * 32);
                    acc[mt] = MFMA16(wf, in[t], acc[mt]);
                }
            }
        };

        auto gemm_lds = [&](int s, bf16x8* in) {
            zero_acc();
#pragma unroll
            for (int mt = 0; mt < 8; ++mt) {
                const int m = mt * 16 + c;
                const char* wrow = smem + s * LDS_W + m * 256;
                const int msw = m & 7;
#pragma unroll
                for (int t = 0; t < 4; ++t) {
                    bf16x8 wf = *(const bf16x8*)(wrow + (((t * 4 + q) ^ msw) * 16));
                    acc[mt] = MFMA16(wf, in[t], acc[mt]);
                }
            }
        };

        // C-space: +bias(fp32) (and relu), pack to bf16, LDS round-trip to
        // B-frag layout; optional residual add; dst regs or fp32 global store.
        auto transition = [&](const float* bias, bool relu, bf16x8* resid,
                              bf16x8* dst, bool to_global) {
#pragma unroll
            for (int p = 0; p < 2; ++p) {  // hidden halves [64p, 64p+64)
#pragma unroll
                for (int mi = 0; mi < 4; ++mi) {
                    const int mt = 4 * p + mi;
                    f32x4 a = acc[mt];
                    f32x4 bv = *(const f32x4*)(bias + mt * 16 + q * 4);
#pragma unroll
                    for (int r = 0; r < 4; ++r) {
                        float v = a[r] + bv[r];
                        if (relu) v = v > 0.f ? v : 0.f;
                        a[r] = v;
                    }
                    bf16x4 pk = {(bf16)a[0], (bf16)a[1], (bf16)a[2], (bf16)a[3]};
                    const int hl = mi * 16 + q * 4;  // local hidden 0..60
                    *(bf16x4*)(stg + c * STG_STRIDE + (((hl >> 3) ^ (c & 7)) * 16) +
                               (hl & 7) * 2) = pk;
                }
                LDS_FENCE();  // cross-lane: writes visible before reads
#pragma unroll
                for (int ti = 0; ti < 2; ++ti) {
                    const int t  = 2 * p + ti;
                    const int kl = ti * 32 + q * 8;
                    bf16x8 sv = *(const bf16x8*)(stg + c * STG_STRIDE +
                                                 (((kl >> 3) ^ (c & 7)) * 16));
                    if (to_global) {
                        float* orow = out + (row0 + c) * 128 + t * 32 + q * 8;
                        bf16x8 rv = resid[t];
                        f32x4 lo, hi;
#pragma unroll
                        for (int j = 0; j < 4; ++j) {
                            lo[j] = (float)sv[j]     + (float)rv[j];
                            hi[j] = (float)sv[4 + j] + (float)rv[4 + j];
                        }
                        *(f32x4*)(orow)     = lo;
                        *(f32x4*)(orow + 4) = hi;
                    } else {
                        if (resid) {
                            bf16x8 rv = resid[t];
                            bf16x8 o;
#pragma unroll
                            for (int j = 0; j < 8; ++j)
                                o[j] = (bf16)((float)sv[j] + (float)rv[j]);
                            sv = o;
                        }
                        dst[t] = sv;
                    }
                }
                LDS_FENCE();  // reads drained before next overwrite (WAR)
            }
        };

        // stage 1: A = W_A x^T + b_A            (weights from global/L2)
        gemm_global(W_A, Xf);
        transition(b_A, false, nullptr, Af, false);
        // stage 2: h = relu(W1eff A^T + b1)
        gemm_lds(0, Af);
        transition(fuse_b1, true, nullptr, Hf, false);
        // stage 3: Ahat = fuse_w2 h^T + b2 + A
        gemm_lds(1, Hf);
        transition(fuse_b2, false, Af, Hf, false);
        // stage 4: h2 = relu(upd_w1 Ahat^T + b3)
        gemm_lds(2, Hf);
        transition(upd_b1, true, nullptr, Af, false);
        // stage 5: out = upd_w2 h2^T + b4 + x   -> fp32 global
        gemm_lds(3, Af);
        transition(upd_b2, false, Xf, nullptr, true);
    }
}

// ---------------- fallback: exact round-0 kernel (measured 179 us) ----------
constexpr int THREADS_V0   = 512;  // 8 waves
constexpr int WAVES_V0     = 8;
constexpr int LDS_TOTAL_V0 = LDS_WEIGHTS + WAVES_V0 * STG_BYTES;  // 147456
constexpr int SLOTS_V0     = 256 * WAVES_V0;  // 2048
constexpr int N_IT_V0      = 4;

__global__ __launch_bounds__(THREADS_V0, 2)
void fsl_main_v0(const float* __restrict__ x,
                 const bf16* __restrict__ W_A,
                 const float* __restrict__ b_A,
                 const bf16* __restrict__ Wmats,
                 const float* __restrict__ fuse_b1,
                 const float* __restrict__ fuse_b2,
                 const float* __restrict__ upd_b1,
                 const float* __restrict__ upd_b2,
                 float* __restrict__ out) {
    extern __shared__ __align__(16) char smem[];
    const int tid  = threadIdx.x;
    const int lane = tid & 63;
    const int wave = tid >> 6;
    const int c    = lane & 15;
    const int q    = lane >> 4;

    {
        uint4 z = {0u, 0u, 0u, 0u};
        for (int i = tid; i < LDS_TOTAL_V0 / 16; i += THREADS_V0)
            ((uint4*)smem)[i] = z;
    }
    __syncthreads();

    for (int g = tid; g < 4 * 128 * 16; g += THREADS_V0) {
        const int s  = g >> 11;
        const int m  = (g >> 4) & 127;
        const int gk = g & 15;
        uint4 v = *(const uint4*)(Wmats + s * 16384 + m * 128 + gk * 8);
        *(uint4*)(smem + s * LDS_W + m * 256 + ((gk ^ (m & 7)) * 16)) = v;
    }
    __syncthreads();

    char* const stg = smem + LDS_WEIGHTS + wave * STG_BYTES;
    const int wslot = blockIdx.x * WAVES_V0 + wave;  // 0..2047

    for (int it = 0; it < N_IT_V0; ++it) {
        const int blk  = wslot + it * SLOTS_V0;  // 0..8191
        const int row0 = blk * 32;

        bf16x8 Xf[2][4], Af[2][4], Hf[2][4];
        f32x4  acc[2][8];

#pragma unroll
        for (int u = 0; u < 2; ++u) {
            const float* xr = x + (row0 + u * 16 + c) * 128 + q * 8;
#pragma unroll
            for (int t = 0; t < 4; ++t) {
                f32x4 lo = *(const f32x4*)(xr + t * 32);
                f32x4 hi = *(const f32x4*)(xr + t * 32 + 4);
                bf16x8 f;
#pragma unroll
                for (int j = 0; j < 4; ++j) {
                    f[j]     = (bf16)lo[j];
                    f[4 + j] = (bf16)hi[j];
                }
                Xf[u][t] = f;
            }
        }

        auto zero_acc = [&]() {
#pragma unroll
            for (int u = 0; u < 2; ++u)
#pragma unroll
                for (int mt = 0; mt < 8; ++mt)
                    acc[u][mt] = f32x4{0.f, 0.f, 0.f, 0.f};
        };

        auto gemm_global = [&](const bf16* W, bf16x8 (&in)[2][4]) {
            zero_acc();
#pragma unroll
            for (int mt = 0; mt < 8; ++mt) {
                const bf16* wrow = W + (mt * 16 + c) * 128 + q * 8;
#pragma unroll
                for (int t = 0; t < 4; ++t) {
                    bf16x8 wf = *(const bf16x8*)(wrow + t * 32);
#pragma unroll
                    for (int u = 0; u < 2; ++u)
                        acc[u][mt] = MFMA16(wf, in[u][t], acc[u][mt]);
                }
            }
        };

        auto gemm_lds = [&](int s, bf16x8 (&in)[2][4]) {
            zero_acc();
#pragma unroll
            for (int mt = 0; mt < 8; ++mt) {
                const int m = mt * 16 + c;
                const char* wrow = smem + s * LDS_W + m * 256;
                const int msw = m & 7;
#pragma unroll
                for (int t = 0; t < 4; ++t) {
                    bf16x8 wf = *(const bf16x8*)(wrow + (((t * 4 + q) ^ msw) * 16));
#pragma unroll
                    for (int u = 0; u < 2; ++u)
                        acc[u][mt] = MFMA16(wf, in[u][t], acc[u][mt]);
                }
            }
        };

        auto transition = [&](const float* bias, bool relu, bf16x8 (*resid)[4],
                              bf16x8 (*dst)[4], bool to_global) {
#pragma unroll
            for (int u = 0; u < 2; ++u) {
#pragma unroll
                for (int p = 0; p < 2; ++p) {
#pragma unroll
                    for (int mi = 0; mi < 4; ++mi) {
                        const int mt = 4 * p + mi;
                        f32x4 a = acc[u][mt];
                        f32x4 bv = *(const f32x4*)(bias + mt * 16 + q * 4);
#pragma unroll
                        for (int r = 0; r < 4; ++r) {
                            float v = a[r] + bv[r];
                            if (relu) v = v > 0.f ? v : 0.f;
                            a[r] = v;
                        }
                        bf16x4 pk = {(bf16)a[0], (bf16)a[1], (bf16)a[2], (bf16)a[3]};
                        const int hl = mi * 16 + q * 4;
                        *(bf16x4*)(stg + c * STG_STRIDE + (((hl >> 3) ^ (c & 7)) * 16) +
                                   (hl & 7) * 2) = pk;
                    }
                    LDS_FENCE();
#pragma unroll
                    for (int ti = 0; ti < 2; ++ti) {
                        const int t  = 2 * p + ti;
                        const int kl = ti * 32 + q * 8;
                        bf16x8 sv = *(const bf16x8*)(stg + c * STG_STRIDE +
                                                     (((kl >> 3) ^ (c & 7)) * 16));
                        if (to_global) {
                            float* orow = out + (row0 + u * 16 + c) * 128 + t * 32 + q * 8;
                            bf16x8 rv = resid[u][t];
                            f32x4 lo, hi;
#pragma unroll
                            for (int j = 0; j < 4; ++j) {
                                lo[j] = (float)sv[j]     + (float)rv[j];
                                hi[j] = (float)sv[4 + j] + (float)rv[4 + j];
                            }
                            *(f32x4*)(orow)     = lo;
                            *(f32x4*)(orow + 4) = hi;
                        } else {
                            if (resid) {
                                bf16x8 rv = resid[u][t];
                                bf16x8 o;
#pragma unroll
                                for (int j = 0; j < 8; ++j)
                                    o[j] = (bf16)((float)sv[j] + (float)rv[j]);
                                sv = o;
                            }
                            dst[u][t] = sv;
                        }
                    }
                    LDS_FENCE();
                }
            }
        };

        gemm_global(W_A, Xf);
        transition(b_A, false, nullptr, Af, false);
        gemm_lds(0, Af);
        transition(fuse_b1, true, nullptr, Hf, false);
        gemm_lds(1, Hf);
        transition(fuse_b2, false, Af, Hf, false);
        gemm_lds(2, Hf);
        transition(upd_b1, true, nullptr, Af, false);
        gemm_lds(3, Af);
        transition(upd_b2, false, Xf, nullptr, true);
    }
}

extern "C" void kernel_launch(void* const* d_in, const int* in_sizes, int n_in,
                              void* d_out, int out_size, void* d_ws, size_t ws_size,
                              hipStream_t stream) {
    const float* task      = (const float*)d_in[0];
    const float* in_proj_w = (const float*)d_in[1];
    const float* in_proj_b = (const float*)d_in[2];
    const float* out_w     = (const float*)d_in[3];
    const float* out_b     = (const float*)d_in[4];
    const float* fuse_w1   = (const float*)d_in[5];
    const float* fuse_b1   = (const float*)d_in[6];
    const float* fuse_w2   = (const float*)d_in[7];
    const float* fuse_b2   = (const float*)d_in[8];
    const float* upd_w1    = (const float*)d_in[9];
    const float* upd_b1    = (const float*)d_in[10];
    const float* upd_w2    = (const float*)d_in[11];
    const float* upd_b2    = (const float*)d_in[12];
    float* out = (float*)d_out;

    // ws layout: W_A (16384 bf16) | Wmats (4*16384 bf16) | b_A (128 f32)
    bf16*  W_A   = (bf16*)d_ws;
    bf16*  Wmats = W_A + 16384;
    float* b_A   = (float*)((char*)d_ws + 32768 + 131072);

    (void)in_sizes; (void)n_in; (void)out_size; (void)ws_size;

    prep_kernel<<<128, 128, 0, stream>>>(in_proj_w, in_proj_b, out_w, out_b,
                                         fuse_w1, fuse_w2, upd_w1, upd_w2,
                                         W_A, Wmats, b_A);

    // Gate: run the slim-wave primary only if it compiled spill-free
    // (host-side attribute query; graph-capture safe).
    hipFuncAttributes fa{};
    bool use_primary = false;
    if (hipFuncGetAttributes(&fa, (const void*)fsl_main) == hipSuccess)
        use_primary = (fa.localSizeBytes == 0);

    if (use_primary) {
        hipFuncSetAttribute((const void*)fsl_main,
                            hipFuncAttributeMaxDynamicSharedMemorySize, LDS_TOTAL);
        fsl_main<<<256, THREADS, LDS_TOTAL, stream>>>(task, W_A, b_A, Wmats,
                                                      fuse_b1, fuse_b2, upd_b1,
                                                      upd_b2, out);
    } else {
        hipFuncSetAttribute((const void*)fsl_main_v0,
                            hipFuncAttributeMaxDynamicSharedMemorySize, LDS_TOTAL_V0);
        fsl_main_v0<<<256, THREADS_V0, LDS_TOTAL_V0, stream>>>(task, W_A, b_A,
                                                               Wmats, fuse_b1,
                                                               fuse_b2, upd_b1,
                                                               upd_b2, out);
    }
}